// Round 1
// baseline (158.857 us; speedup 1.0000x reference)
//
#include <hip/hip_runtime.h>
#include <math.h>

#define BATCH 8
#define NPTS  4096           // P == Q
#define QCHUNK 512           // cols staged per block
#define RPB    256           // rows per block
#define WCOLS  (QCHUNK / 4)  // cols per wave (4 waves/block)

// ---------------------------------------------------------------------------
// bpp: sum(-log2(lik)) over all elements, accumulated into ws float.
// ---------------------------------------------------------------------------
__global__ __launch_bounds__(256) void bpp_kernel(const float* __restrict__ lik,
                                                  float* __restrict__ bppSum) {
    int idx = blockIdx.x * 256 + threadIdx.x;
    const float4* l4 = (const float4*)lik;
    float4 v = l4[idx];
    // product of 4 values in (1e-6, 1]: min 1e-24, no underflow in f32
    float s = -__log2f(v.x * v.y * v.z * v.w);
    #pragma unroll
    for (int off = 32; off >= 1; off >>= 1) s += __shfl_down(s, off, 64);
    __shared__ float wsum[4];
    int lane = threadIdx.x & 63, w = threadIdx.x >> 6;
    if (lane == 0) wsum[w] = s;
    __syncthreads();
    if (threadIdx.x == 0)
        atomicAdd(bppSum, wsum[0] + wsum[1] + wsum[2] + wsum[3]);
}

// ---------------------------------------------------------------------------
// nnmin: for each row p of X (per batch), min over this block's col-chunk of
//   d2 = |X[b,p] - Y[b,q]|^2 (clamped >= 0), atomicMin'd (uint trick) into
//   outMin[b*NPTS + p]. Run twice with (X,Y) swapped for both directions.
// Block: 256 thr = 4 waves; 256 rows x 512 cols tile; wave w owns 128 cols;
// each lane owns 4 rows (lane + {0,64,128,192}).
// ---------------------------------------------------------------------------
__global__ __launch_bounds__(256) void nnmin_kernel(const float* __restrict__ X,
                                                    const float* __restrict__ Y,
                                                    unsigned int* __restrict__ outMin) {
    const int b = blockIdx.y;
    const int nQB = NPTS / QCHUNK;           // 8
    const int rowBlk = (int)blockIdx.x / nQB;
    const int qBlk   = (int)blockIdx.x % nQB;
    const int rowBase = rowBlk * RPB;
    const int colBase = qBlk * QCHUNK;

    __shared__ float4 ys[QCHUNK];
    __shared__ float  rpart[4 * RPB];

    // stage Y points + squared norms
    for (int i = threadIdx.x; i < QCHUNK; i += 256) {
        const float* p = Y + ((size_t)b * NPTS + colBase + i) * 3;
        float y0 = p[0], y1 = p[1], y2 = p[2];
        ys[i] = make_float4(y0, y1, y2, y0 * y0 + y1 * y1 + y2 * y2);
    }
    __syncthreads();

    const int lane = threadIdx.x & 63;
    const int w    = threadIdx.x >> 6;

    float x0[4], x1[4], x2[4], xn[4], rmin[4];
    #pragma unroll
    for (int i = 0; i < 4; ++i) {
        const float* p = X + ((size_t)b * NPTS + rowBase + i * 64 + lane) * 3;
        x0[i] = p[0]; x1[i] = p[1]; x2[i] = p[2];
        xn[i] = x0[i] * x0[i] + x1[i] * x1[i] + x2[i] * x2[i];
        rmin[i] = 3.0e38f;
    }

    const float4* yw = ys + w * WCOLS;
    #pragma unroll 4
    for (int q = 0; q < WCOLS; ++q) {
        float4 y = yw[q];
        #pragma unroll
        for (int i = 0; i < 4; ++i) {
            float dot = x0[i] * y.x + x1[i] * y.y + x2[i] * y.z;
            float d2  = (xn[i] + y.w) - 2.0f * dot;
            d2 = fmaxf(d2, 0.0f);
            rmin[i] = fminf(rmin[i], d2);
        }
    }

    #pragma unroll
    for (int i = 0; i < 4; ++i)
        rpart[w * RPB + i * 64 + lane] = rmin[i];
    __syncthreads();

    // combine the 4 waves' disjoint col-chunks; one atomic per row per block
    int r = threadIdx.x;  // 0..255 == row within block
    float m = fminf(fminf(rpart[r], rpart[RPB + r]),
                    fminf(rpart[2 * RPB + r], rpart[3 * RPB + r]));
    atomicMin(&outMin[(size_t)b * NPTS + rowBase + r], __float_as_uint(m));
}

// ---------------------------------------------------------------------------
// final: rec = (sum rowMin + sum colMin)/32768; bpp = bppSum/32768
// out = {loss, bpp, rec}
// ---------------------------------------------------------------------------
__global__ __launch_bounds__(256) void final_kernel(const unsigned int* __restrict__ mins,
                                                    const float* __restrict__ bppSum,
                                                    float* __restrict__ out) {
    const int N = 2 * BATCH * NPTS;  // 65536
    float s = 0.0f;
    for (int i = threadIdx.x; i < N; i += 256)
        s += __uint_as_float(mins[i]);
    #pragma unroll
    for (int off = 32; off >= 1; off >>= 1) s += __shfl_down(s, off, 64);
    __shared__ float wsum[4];
    int lane = threadIdx.x & 63, w = threadIdx.x >> 6;
    if (lane == 0) wsum[w] = s;
    __syncthreads();
    if (threadIdx.x == 0) {
        float rec = (wsum[0] + wsum[1] + wsum[2] + wsum[3]) * (1.0f / 32768.0f);
        float bpp = (*bppSum) * (1.0f / 32768.0f);
        out[0] = rec + bpp;
        out[1] = bpp;
        out[2] = rec;
    }
}

extern "C" void kernel_launch(void* const* d_in, const int* in_sizes, int n_in,
                              void* d_out, int out_size, void* d_ws, size_t ws_size,
                              hipStream_t stream) {
    const float* x_hat = (const float*)d_in[0];
    const float* pos   = (const float*)d_in[1];
    const float* lik   = (const float*)d_in[2];
    float* out = (float*)d_out;

    // workspace layout:
    //   [0, 256):               float bppSum (zeroed)
    //   [256, 256+128K):        rowMin  (B*P uints, init +huge)
    //   [256+128K, 256+256K):   colMin  (B*P uints, init +huge)
    char* ws = (char*)d_ws;
    float* bppSum = (float*)ws;
    unsigned int* rowMin = (unsigned int*)(ws + 256);
    unsigned int* colMin = rowMin + (size_t)BATCH * NPTS;
    unsigned int* mins   = rowMin;  // contiguous rowMin||colMin

    hipMemsetAsync(ws, 0, 256, stream);
    // 0x7F7F7F7F as float = 3.39e38 — acts as +inf for all realistic d2
    hipMemsetAsync(ws + 256, 0x7F, 2 * (size_t)BATCH * NPTS * sizeof(unsigned int), stream);

    int nl4 = in_sizes[2] / 4;               // 393216
    bpp_kernel<<<nl4 / 256, 256, 0, stream>>>(lik, bppSum);

    dim3 grid((NPTS / RPB) * (NPTS / QCHUNK), BATCH);  // (128, 8) = 1024 blocks
    nnmin_kernel<<<grid, 256, 0, stream>>>(x_hat, pos, rowMin);  // x -> y
    nnmin_kernel<<<grid, 256, 0, stream>>>(pos, x_hat, colMin);  // y -> x

    final_kernel<<<1, 256, 0, stream>>>(mins, bppSum, out);
}

// Round 2
// 58.939 us; speedup vs baseline: 2.6953x; 2.6953x over previous
//
#include <hip/hip_runtime.h>
#include <math.h>

#define BATCH  8
#define NPTS   4096
#define QCHUNK 512          // cols staged per block
#define RPB    512          // rows per block
#define NR     8            // rows per lane (RPB / 64)
#define WCOLS  (QCHUNK / 4) // cols per wave (4 waves/block)

// ---------------------------------------------------------------------------
// bpp: sum(-log2(lik)) over all elements, accumulated into ws float.
// ---------------------------------------------------------------------------
__global__ __launch_bounds__(256) void bpp_kernel(const float* __restrict__ lik,
                                                  float* __restrict__ bppSum) {
    int idx = blockIdx.x * 256 + threadIdx.x;
    const float4* l4 = (const float4*)lik;
    float4 v = l4[idx];
    // product of 4 values in (1e-6, 1]: min 1e-24, no underflow in f32
    float s = -__log2f(v.x * v.y * v.z * v.w);
    #pragma unroll
    for (int off = 32; off >= 1; off >>= 1) s += __shfl_down(s, off, 64);
    __shared__ float wsum[4];
    int lane = threadIdx.x & 63, w = threadIdx.x >> 6;
    if (lane == 0) wsum[w] = s;
    __syncthreads();
    if (threadIdx.x == 0)
        atomicAdd(bppSum, wsum[0] + wsum[1] + wsum[2] + wsum[3]);
}

// ---------------------------------------------------------------------------
// nnmin: both chamfer directions in one dispatch (blockIdx.z).
// Block = 256 thr (4 waves) covers RPB=512 rows x QCHUNK=512 cols.
// Each lane owns NR=8 rows (regs); wave w sweeps cols [w*128,(w+1)*128) of the
// staged chunk. Inner body: t = y.w - 2*x.y via 3 FMA (x pre-scaled by -2),
// then fmin. Row norm xn and the >=0 clamp are deferred to the epilogue
// (both commute with min). One atomicMin (uint trick) per row per block.
// ---------------------------------------------------------------------------
__global__ __launch_bounds__(256) void nnmin_kernel(const float* __restrict__ A,
                                                    const float* __restrict__ B,
                                                    unsigned int* __restrict__ out0,
                                                    unsigned int* __restrict__ out1) {
    const float* X; const float* Y; unsigned int* outMin;
    if (blockIdx.z == 0) { X = A; Y = B; outMin = out0; }
    else                 { X = B; Y = A; outMin = out1; }

    const int b = blockIdx.y;
    const int nQB = NPTS / QCHUNK;           // 8
    const int rowBlk = (int)blockIdx.x / nQB;
    const int qBlk   = (int)blockIdx.x % nQB;
    const int rowBase = rowBlk * RPB;
    const int colBase = qBlk * QCHUNK;

    __shared__ float4 ys[QCHUNK];            // 8 KB
    __shared__ float  rpart[4][RPB];         // 8 KB

    // stage Y points + squared norms (2 points per thread)
    for (int i = threadIdx.x; i < QCHUNK; i += 256) {
        const float* p = Y + ((size_t)b * NPTS + colBase + i) * 3;
        float y0 = p[0], y1 = p[1], y2 = p[2];
        ys[i] = make_float4(y0, y1, y2, y0 * y0 + y1 * y1 + y2 * y2);
    }
    __syncthreads();

    const int lane = threadIdx.x & 63;
    const int w    = threadIdx.x >> 6;

    float s0[NR], s1[NR], s2[NR], rmin[NR];
    #pragma unroll
    for (int i = 0; i < NR; ++i) {
        const float* p = X + ((size_t)b * NPTS + rowBase + i * 64 + lane) * 3;
        s0[i] = -2.0f * p[0]; s1[i] = -2.0f * p[1]; s2[i] = -2.0f * p[2];
        rmin[i] = 3.0e38f;
    }

    const float4* yw = ys + w * WCOLS;
    #pragma unroll 2
    for (int q = 0; q < WCOLS; ++q) {
        float4 y = yw[q];
        #pragma unroll
        for (int i = 0; i < NR; ++i) {
            float t = fmaf(s2[i], y.z, y.w);
            t = fmaf(s1[i], y.y, t);
            t = fmaf(s0[i], y.x, t);
            rmin[i] = fminf(rmin[i], t);
        }
    }

    #pragma unroll
    for (int i = 0; i < NR; ++i)
        rpart[w][i * 64 + lane] = rmin[i];
    __syncthreads();

    // combine 4 waves' disjoint col-chunks; add xn, clamp, one atomic per row
    for (int r = threadIdx.x; r < RPB; r += 256) {
        float m = fminf(fminf(rpart[0][r], rpart[1][r]),
                        fminf(rpart[2][r], rpart[3][r]));
        const float* p = X + ((size_t)b * NPTS + rowBase + r) * 3;
        float xn = p[0] * p[0] + p[1] * p[1] + p[2] * p[2];
        m = fmaxf(xn + m, 0.0f);
        atomicMin(&outMin[(size_t)b * NPTS + rowBase + r], __float_as_uint(m));
    }
}

// ---------------------------------------------------------------------------
// reduce: sum the 65536 row/col mins (stored as non-negative float bits) into
// recSum. 64 blocks x 256 threads, float4 loads, one atomic per block.
// ---------------------------------------------------------------------------
__global__ __launch_bounds__(256) void reduce_kernel(const float* __restrict__ mins,
                                                     float* __restrict__ recSum) {
    int idx = blockIdx.x * 256 + threadIdx.x;
    const float4* m4 = (const float4*)mins;
    float4 v = m4[idx];
    float s = (v.x + v.y) + (v.z + v.w);
    #pragma unroll
    for (int off = 32; off >= 1; off >>= 1) s += __shfl_down(s, off, 64);
    __shared__ float wsum[4];
    int lane = threadIdx.x & 63, w = threadIdx.x >> 6;
    if (lane == 0) wsum[w] = s;
    __syncthreads();
    if (threadIdx.x == 0)
        atomicAdd(recSum, wsum[0] + wsum[1] + wsum[2] + wsum[3]);
}

// ---------------------------------------------------------------------------
// final: out = {rec+bpp, bpp, rec}
// ---------------------------------------------------------------------------
__global__ void final_kernel(const float* __restrict__ sums,  // [bpp, rec]
                             float* __restrict__ out) {
    if (threadIdx.x == 0) {
        float bpp = sums[0] * (1.0f / 32768.0f);
        float rec = sums[1] * (1.0f / 32768.0f);
        out[0] = rec + bpp;
        out[1] = bpp;
        out[2] = rec;
    }
}

extern "C" void kernel_launch(void* const* d_in, const int* in_sizes, int n_in,
                              void* d_out, int out_size, void* d_ws, size_t ws_size,
                              hipStream_t stream) {
    const float* x_hat = (const float*)d_in[0];
    const float* pos   = (const float*)d_in[1];
    const float* lik   = (const float*)d_in[2];
    float* out = (float*)d_out;

    // workspace layout:
    //   [0,4):       float bppSum   (zeroed)
    //   [4,8):       float recSum   (zeroed)
    //   [256, +256K) rowMin || colMin (2*B*P uints, init 0x7F7F7F7F = 3.39e38)
    char* ws = (char*)d_ws;
    float* sums = (float*)ws;                       // [bppSum, recSum]
    unsigned int* rowMin = (unsigned int*)(ws + 256);
    unsigned int* colMin = rowMin + (size_t)BATCH * NPTS;
    const float* mins = (const float*)rowMin;       // contiguous rowMin||colMin

    hipMemsetAsync(ws, 0, 256, stream);
    hipMemsetAsync(ws + 256, 0x7F, 2 * (size_t)BATCH * NPTS * sizeof(unsigned int), stream);

    int nl4 = in_sizes[2] / 4;                      // 393216
    bpp_kernel<<<nl4 / 256, 256, 0, stream>>>(lik, sums);

    dim3 grid((NPTS / RPB) * (NPTS / QCHUNK), BATCH, 2);  // (64, 8, 2) = 1024 blocks
    nnmin_kernel<<<grid, 256, 0, stream>>>(x_hat, pos, rowMin, colMin);

    reduce_kernel<<<(2 * BATCH * NPTS) / 4 / 256, 256, 0, stream>>>(mins, sums + 1);
    final_kernel<<<1, 64, 0, stream>>>(sums, out);
}

// Round 3
// 42.943 us; speedup vs baseline: 3.6992x; 1.3725x over previous
//
#include <hip/hip_runtime.h>
#include <math.h>

#define BATCH  8
#define NPTS   4096
#define QCHUNK 512          // cols staged per LDS chunk
#define NCHUNK (NPTS / QCHUNK)  // 8
#define RPB    128          // rows per block
#define NR     2            // rows per lane (RPB / 64)
#define WCOLS  (QCHUNK / 4) // cols per wave per chunk (4 waves/block)

#define NBPP_BLOCKS 1536    // 393216 float4s / 256
#define NNN_BLOCKS  512     // (NPTS/RPB) * BATCH * 2

// ---------------------------------------------------------------------------
// bpp: per-block partial of sum(-log2(lik)); no atomics, no init needed.
// ---------------------------------------------------------------------------
__global__ __launch_bounds__(256) void bpp_kernel(const float* __restrict__ lik,
                                                  float* __restrict__ bppPartial) {
    int idx = blockIdx.x * 256 + threadIdx.x;
    const float4* l4 = (const float4*)lik;
    float4 v = l4[idx];
    // product of 4 values in (1e-6, 1]: min 1e-24, no underflow in f32
    float s = -__log2f(v.x * v.y * v.z * v.w);
    #pragma unroll
    for (int off = 32; off >= 1; off >>= 1) s += __shfl_down(s, off, 64);
    __shared__ float wsum[4];
    int lane = threadIdx.x & 63, w = threadIdx.x >> 6;
    if (lane == 0) wsum[w] = s;
    __syncthreads();
    if (threadIdx.x == 0)
        bppPartial[blockIdx.x] = wsum[0] + wsum[1] + wsum[2] + wsum[3];
}

// ---------------------------------------------------------------------------
// nnmin: both chamfer directions in one dispatch (blockIdx.z selects X,Y).
// Block = 256 thr (4 waves) owns RPB=128 rows and loops over ALL 4096 cols
// in 8 LDS chunks of 512. Each lane holds NR=2 rows; wave w sweeps its
// 128-col quarter of each chunk. Inner body: 3 FMA (x pre-scaled by -2,
// |y|^2 as the FMA seed) + 1 min. Row norm & clamp deferred to epilogue.
// Each block emits ONE partial sum of its rows' minima -> recPartial[blk].
// No atomics, no workspace init.
// ---------------------------------------------------------------------------
__global__ __launch_bounds__(256) void nnmin_kernel(const float* __restrict__ A,
                                                    const float* __restrict__ B,
                                                    float* __restrict__ recPartial) {
    const float* X; const float* Y;
    if (blockIdx.z == 0) { X = A; Y = B; }
    else                 { X = B; Y = A; }

    const int b = blockIdx.y;
    const int rowBase = (int)blockIdx.x * RPB;

    __shared__ float4 ys[QCHUNK];        // 8 KB
    __shared__ float  rpart[4][RPB];     // 2 KB
    __shared__ float  xns[RPB];          // 0.5 KB
    __shared__ float  rsum[RPB];         // 0.5 KB

    const int lane = threadIdx.x & 63;
    const int w    = threadIdx.x >> 6;

    float s0[NR], s1[NR], s2[NR], rmin[NR];
    #pragma unroll
    for (int i = 0; i < NR; ++i) {
        const float* p = X + ((size_t)b * NPTS + rowBase + i * 64 + lane) * 3;
        float x0 = p[0], x1 = p[1], x2 = p[2];
        s0[i] = -2.0f * x0; s1[i] = -2.0f * x1; s2[i] = -2.0f * x2;
        if (w == 0) xns[i * 64 + lane] = x0 * x0 + x1 * x1 + x2 * x2;
        rmin[i] = 3.0e38f;
    }

    for (int c = 0; c < NCHUNK; ++c) {
        __syncthreads();   // also protects xns on first iteration
        // stage chunk c of Y: 512 points + squared norms (2 per thread)
        for (int i = threadIdx.x; i < QCHUNK; i += 256) {
            const float* p = Y + ((size_t)b * NPTS + c * QCHUNK + i) * 3;
            float y0 = p[0], y1 = p[1], y2 = p[2];
            ys[i] = make_float4(y0, y1, y2, y0 * y0 + y1 * y1 + y2 * y2);
        }
        __syncthreads();

        const float4* yw = ys + w * WCOLS;
        #pragma unroll 4
        for (int q = 0; q < WCOLS; ++q) {
            float4 y = yw[q];
            #pragma unroll
            for (int i = 0; i < NR; ++i) {
                float t = fmaf(s2[i], y.z, y.w);
                t = fmaf(s1[i], y.y, t);
                t = fmaf(s0[i], y.x, t);
                rmin[i] = fminf(rmin[i], t);
            }
        }
    }

    #pragma unroll
    for (int i = 0; i < NR; ++i)
        rpart[w][i * 64 + lane] = rmin[i];
    __syncthreads();

    // combine 4 waves per row, add row norm, clamp, then block-sum the rows
    if (threadIdx.x < RPB) {
        int r = threadIdx.x;
        float m = fminf(fminf(rpart[0][r], rpart[1][r]),
                        fminf(rpart[2][r], rpart[3][r]));
        rsum[r] = fmaxf(xns[r] + m, 0.0f);
    }
    __syncthreads();

    if (threadIdx.x < 64) {
        float s = rsum[threadIdx.x] + rsum[threadIdx.x + 64];
        #pragma unroll
        for (int off = 32; off >= 1; off >>= 1) s += __shfl_down(s, off, 64);
        if (threadIdx.x == 0) {
            int blk = ((int)blockIdx.z * gridDim.y + blockIdx.y) * gridDim.x + blockIdx.x;
            recPartial[blk] = s;
        }
    }
}

// ---------------------------------------------------------------------------
// final: sum both partial arrays; out = {rec+bpp, bpp, rec}
// ---------------------------------------------------------------------------
__global__ __launch_bounds__(256) void final_kernel(const float* __restrict__ bppPartial,
                                                    const float* __restrict__ recPartial,
                                                    float* __restrict__ out) {
    float sb = 0.0f, sr = 0.0f;
    for (int i = threadIdx.x; i < NBPP_BLOCKS; i += 256) sb += bppPartial[i];
    for (int i = threadIdx.x; i < NNN_BLOCKS; i += 256)  sr += recPartial[i];
    #pragma unroll
    for (int off = 32; off >= 1; off >>= 1) {
        sb += __shfl_down(sb, off, 64);
        sr += __shfl_down(sr, off, 64);
    }
    __shared__ float wb[4], wr[4];
    int lane = threadIdx.x & 63, w = threadIdx.x >> 6;
    if (lane == 0) { wb[w] = sb; wr[w] = sr; }
    __syncthreads();
    if (threadIdx.x == 0) {
        float bpp = (wb[0] + wb[1] + wb[2] + wb[3]) * (1.0f / 32768.0f);
        float rec = (wr[0] + wr[1] + wr[2] + wr[3]) * (1.0f / 32768.0f);
        out[0] = rec + bpp;
        out[1] = bpp;
        out[2] = rec;
    }
}

extern "C" void kernel_launch(void* const* d_in, const int* in_sizes, int n_in,
                              void* d_out, int out_size, void* d_ws, size_t ws_size,
                              hipStream_t stream) {
    const float* x_hat = (const float*)d_in[0];
    const float* pos   = (const float*)d_in[1];
    const float* lik   = (const float*)d_in[2];
    float* out = (float*)d_out;

    // workspace: [0, 1536) bpp partials | [1536, 1536+512) rec partials
    float* bppPartial = (float*)d_ws;
    float* recPartial = bppPartial + NBPP_BLOCKS;

    bpp_kernel<<<NBPP_BLOCKS, 256, 0, stream>>>(lik, bppPartial);

    dim3 grid(NPTS / RPB, BATCH, 2);   // (32, 8, 2) = 512 blocks
    nnmin_kernel<<<grid, 256, 0, stream>>>(x_hat, pos, recPartial);

    final_kernel<<<1, 256, 0, stream>>>(bppPartial, recPartial, out);
}

// Round 4
// 32.219 us; speedup vs baseline: 4.9305x; 1.3328x over previous
//
#include <hip/hip_runtime.h>
#include <math.h>

#define BATCH   8
#define NPTS    4096
#define QCHUNK  512
#define NCHUNK  (NPTS / QCHUNK)       // 8
#define THREADS 512
#define WAVES   8
#define WCOLS   (QCHUNK / WAVES)      // 64 cols per wave per chunk
#define RPB     128                   // rows per block
#define NR      2                     // rows per lane
#define NBLOCKS ((NPTS / RPB) * BATCH * 2)   // 512

#define LIK_F4      393216            // 8*192*1024 / 4
#define LIK_PER_BLK (LIK_F4 / NBLOCKS)  // 768

// ---------------------------------------------------------------------------
// fused: chamfer nnmin partial sums (both directions via blockIdx.z) + a
// per-block slice of the bpp sum. No atomics, no workspace init.
// Block = 512 thr (8 waves) owns RPB=128 rows, loops all 4096 cols in 8
// double-buffered LDS chunks. Next chunk's points are loaded to registers
// BEFORE the compute phase (latency hides under ~512 VALU instrs), written
// to the other LDS buffer after. Inner body: 3 FMA (x pre-scaled by -2,
// |y|^2 as seed) + 1 min; row norm & clamp deferred to epilogue.
// ---------------------------------------------------------------------------
__global__ __launch_bounds__(THREADS) void fused_kernel(
    const float* __restrict__ A, const float* __restrict__ B,
    const float* __restrict__ lik,
    float* __restrict__ recPartial, float* __restrict__ bppPartial)
{
    const float* X; const float* Y;
    if (blockIdx.z == 0) { X = A; Y = B; }
    else                 { X = B; Y = A; }

    const int b = blockIdx.y;
    const int rowBase = (int)blockIdx.x * RPB;
    const int blk = ((int)blockIdx.z * gridDim.y + blockIdx.y) * gridDim.x + blockIdx.x;

    __shared__ float4 ys[2][QCHUNK];     // 16 KB double buffer
    __shared__ float  rpart[WAVES][RPB]; // 4 KB
    __shared__ float  xns[RPB];
    __shared__ float  rsum[RPB];
    __shared__ float  bw[WAVES];

    const int tid  = threadIdx.x;
    const int lane = tid & 63;
    const int w    = tid >> 6;

    // ---- bpp slice: 768 float4s per block ----
    float bs = 0.0f;
    {
        const float4* l4 = (const float4*)lik + (size_t)blk * LIK_PER_BLK;
        for (int i = tid; i < LIK_PER_BLK; i += THREADS) {
            float4 v = l4[i];
            // product of 4 values in (1e-6,1]: min 1e-24, no f32 underflow
            bs -= __log2f(v.x * v.y * v.z * v.w);
        }
    }

    // ---- X rows into registers (all waves hold the same 128 rows) ----
    float s0[NR], s1[NR], s2[NR], rmin[NR];
    #pragma unroll
    for (int i = 0; i < NR; ++i) {
        const float* p = X + ((size_t)b * NPTS + rowBase + i * 64 + lane) * 3;
        float x0 = p[0], x1 = p[1], x2 = p[2];
        s0[i] = -2.0f * x0; s1[i] = -2.0f * x1; s2[i] = -2.0f * x2;
        if (w == 0) xns[i * 64 + lane] = fmaf(x0, x0, fmaf(x1, x1, x2 * x2));
        rmin[i] = 3.0e38f;
    }

    // ---- main loop: double-buffered Y chunks, 1 point staged per thread ----
    float y0, y1, y2;
    {
        const float* p = Y + ((size_t)b * NPTS + tid) * 3;
        y0 = p[0]; y1 = p[1]; y2 = p[2];
        ys[0][tid] = make_float4(y0, y1, y2, fmaf(y0, y0, fmaf(y1, y1, y2 * y2)));
    }
    __syncthreads();

    for (int c = 0; c < NCHUNK; ++c) {
        if (c + 1 < NCHUNK) {   // issue next chunk's loads (hide under compute)
            const float* p = Y + ((size_t)b * NPTS + (c + 1) * QCHUNK + tid) * 3;
            y0 = p[0]; y1 = p[1]; y2 = p[2];
        }

        const float4* yw = ys[c & 1] + w * WCOLS;
        #pragma unroll 4
        for (int q = 0; q < WCOLS; ++q) {
            float4 y = yw[q];
            #pragma unroll
            for (int i = 0; i < NR; ++i) {
                float t = fmaf(s2[i], y.z, y.w);
                t = fmaf(s1[i], y.y, t);
                t = fmaf(s0[i], y.x, t);
                rmin[i] = fminf(rmin[i], t);
            }
        }

        if (c + 1 < NCHUNK) {
            ys[(c + 1) & 1][tid] =
                make_float4(y0, y1, y2, fmaf(y0, y0, fmaf(y1, y1, y2 * y2)));
        }
        __syncthreads();
    }

    // ---- epilogue ----
    #pragma unroll
    for (int i = 0; i < NR; ++i)
        rpart[w][i * 64 + lane] = rmin[i];

    #pragma unroll
    for (int off = 32; off >= 1; off >>= 1) bs += __shfl_down(bs, off, 64);
    if (lane == 0) bw[w] = bs;
    __syncthreads();

    if (tid < RPB) {
        float m = rpart[0][tid];
        #pragma unroll
        for (int j = 1; j < WAVES; ++j) m = fminf(m, rpart[j][tid]);
        rsum[tid] = fmaxf(xns[tid] + m, 0.0f);
    }
    __syncthreads();

    if (tid < 64) {
        float s = rsum[tid] + rsum[tid + 64];
        #pragma unroll
        for (int off = 32; off >= 1; off >>= 1) s += __shfl_down(s, off, 64);
        if (tid == 0) {
            recPartial[blk] = s;
            float bb = bw[0];
            #pragma unroll
            for (int j = 1; j < WAVES; ++j) bb += bw[j];
            bppPartial[blk] = bb;
        }
    }
}

// ---------------------------------------------------------------------------
// final: sum the two 512-entry partial arrays; out = {rec+bpp, bpp, rec}
// ---------------------------------------------------------------------------
__global__ __launch_bounds__(256) void final_kernel(const float* __restrict__ recPartial,
                                                    const float* __restrict__ bppPartial,
                                                    float* __restrict__ out) {
    float sr = 0.0f, sb = 0.0f;
    for (int i = threadIdx.x; i < NBLOCKS; i += 256) {
        sr += recPartial[i];
        sb += bppPartial[i];
    }
    #pragma unroll
    for (int off = 32; off >= 1; off >>= 1) {
        sr += __shfl_down(sr, off, 64);
        sb += __shfl_down(sb, off, 64);
    }
    __shared__ float wr[4], wb[4];
    int lane = threadIdx.x & 63, w = threadIdx.x >> 6;
    if (lane == 0) { wr[w] = sr; wb[w] = sb; }
    __syncthreads();
    if (threadIdx.x == 0) {
        float rec = (wr[0] + wr[1] + wr[2] + wr[3]) * (1.0f / 32768.0f);
        float bpp = (wb[0] + wb[1] + wb[2] + wb[3]) * (1.0f / 32768.0f);
        out[0] = rec + bpp;
        out[1] = bpp;
        out[2] = rec;
    }
}

extern "C" void kernel_launch(void* const* d_in, const int* in_sizes, int n_in,
                              void* d_out, int out_size, void* d_ws, size_t ws_size,
                              hipStream_t stream) {
    const float* x_hat = (const float*)d_in[0];
    const float* pos   = (const float*)d_in[1];
    const float* lik   = (const float*)d_in[2];
    float* out = (float*)d_out;

    // workspace: [0,512) rec partials | [512,1024) bpp partials (floats)
    float* recPartial = (float*)d_ws;
    float* bppPartial = recPartial + NBLOCKS;

    dim3 grid(NPTS / RPB, BATCH, 2);   // (32, 8, 2) = 512 blocks
    fused_kernel<<<grid, THREADS, 0, stream>>>(x_hat, pos, lik, recPartial, bppPartial);
    final_kernel<<<1, 256, 0, stream>>>(recPartial, bppPartial, out);
}